// Round 7
// baseline (102.455 us; speedup 1.0000x reference)
//
#include <hip/hip_runtime.h>
#include <math.h>

// ---------------------------------------------------------------------------
// Fused mesh-loss -> single f32 scalar. V=10000 (100x100 grid), F=19602, E edges.
// R6 restructure: 2 dispatches, zero init work.
//  mid: pure chamfer. 975 uniform blocks (3 dirs x 5 rowblocks x 65 chunks),
//       x-fragments + LDS y-tiles computed on the fly from verts/deform/trg
//       (no precomputed tables, no init kernel). Per-chunk row-min written by
//       PLAIN STORE into minpart[dir][chunk][row] (each slot written exactly
//       once -> no atomicMin, no 0xFF poison pass). Block 0 zeroes out[0].
//  fin: vertex gather (normals + cot-laplacian, newv recomputed on the fly) +
//       edge normal-consistency + quad edge/smooth roles + 195-slice coalesced
//       min-reduce + weighted sum -> atomicAdd out[0].
// Symmetry chamfer: d2 symmetric under flip -> one direction, weight 0.2.
// Fixed floor in the timed window: harness 268MB ws-poison fill (~41us).
// ---------------------------------------------------------------------------

#define EPS_VN 1e-6f
#define EPS_COS 1e-8f
#define CHUNKS 65
#define MAXTILE 160                // ceil(10000/65)=154
#define RPT 8                      // chamfer rows per thread
#define ROWS_PER_BLOCK (256 * RPT) // 2048

struct F3 { float x, y, z; };
__device__ inline F3 ld3(const float* __restrict__ p, int i) {
    return {p[3*i], p[3*i+1], p[3*i+2]};
}
__device__ inline F3 sub3(F3 a, F3 b) { return {a.x-b.x, a.y-b.y, a.z-b.z}; }
__device__ inline F3 add3(F3 a, F3 b) { return {a.x+b.x, a.y+b.y, a.z+b.z}; }
__device__ inline F3 crs3(F3 a, F3 b) {
    return {a.y*b.z - a.z*b.y, a.z*b.x - a.x*b.z, a.x*b.y - a.y*b.x};
}
__device__ inline float dot3(F3 a, F3 b) { return a.x*b.x + a.y*b.y + a.z*b.z; }
__device__ inline float len3(F3 a) { return sqrtf(dot3(a, a)); }
__device__ inline float l1d(F3 a, F3 b) {
    return fabsf(a.x-b.x) + fabsf(a.y-b.y) + fabsf(a.z-b.z);
}

// Valid result in thread 0 only.
__device__ inline float blockReduceSum(float v, float* sbuf) {
    __syncthreads();
    #pragma unroll
    for (int off = 32; off > 0; off >>= 1) v += __shfl_down(v, off, 64);
    int lane = threadIdx.x & 63;
    int wid  = threadIdx.x >> 6;
    if (lane == 0) sbuf[wid] = v;
    __syncthreads();
    float r = 0.0f;
    if (threadIdx.x == 0) {
        int nw = (blockDim.x + 63) >> 6;
        r = sbuf[0];
        for (int w = 1; w < nw; ++w) r += sbuf[w];
    }
    return r;
}

// cots of tri (p0,p1,p2), reference formula (Heron area, clamp 1e-12)
__device__ inline void tri_cots(F3 p0, F3 p1, F3 p2,
                                float& c0, float& c1, float& c2) {
    float a = len3(sub3(p1, p2));
    float b = len3(sub3(p0, p2));
    float c = len3(sub3(p0, p1));
    float s = 0.5f * (a + b + c);
    float area = sqrtf(fmaxf(s*(s-a)*(s-b)*(s-c), 1e-12f));
    float inv4a = 1.0f / (4.0f * area);
    float a2 = a*a, b2 = b*b, c2q = c*c;
    c0 = (b2 + c2q - a2) * inv4a;
    c1 = (a2 + c2q - b2) * inv4a;
    c2 = (a2 + b2 - c2q) * inv4a;
}

// chamfer operand builders (computed on the fly from raw inputs)
__device__ inline float4 x_frag(const float* __restrict__ verts,
                                const float* __restrict__ deform,
                                const float* __restrict__ trg,
                                int dir, int i) {
    if (dir == 1) {
        F3 t = ld3(trg, i);
        return make_float4(t.x, t.y, t.z, dot3(t, t));
    }
    F3 n = add3(ld3(verts, i), ld3(deform, i));
    return make_float4(n.x, n.y, n.z, dot3(n, n));
}
__device__ inline float4 y_frag(const float* __restrict__ verts,
                                const float* __restrict__ deform,
                                const float* __restrict__ trg,
                                int dir, int j) {
    if (dir == 0) {
        F3 t = ld3(trg, j);
        return make_float4(-2.f*t.x, -2.f*t.y, -2.f*t.z, dot3(t, t));
    }
    F3 n = add3(ld3(verts, j), ld3(deform, j));
    float nn = dot3(n, n);
    if (dir == 1) return make_float4(-2.f*n.x, -2.f*n.y, -2.f*n.z, nn);
    return make_float4( 2.f*n.x, -2.f*n.y, -2.f*n.z, nn);  // flip(newv)
}

// ---------------- K1: chamfer partial mins ----------------
__global__ void mid_kernel(const float* __restrict__ verts,
                           const float* __restrict__ deform,
                           const float* __restrict__ trg,
                           int V,
                           float* __restrict__ minpart,   // [3*CHUNKS][V]
                           float* __restrict__ out) {
    __shared__ float4 ytile[MAXTILE];
    int b = blockIdx.x;
    if (b == 0 && threadIdx.x == 0) out[0] = 0.0f;   // mid precedes fin

    int RB  = (V + ROWS_PER_BLOCK - 1) / ROWS_PER_BLOCK;   // 5
    int per = RB * CHUNKS;
    int dir = b / per;
    int rem = b % per;
    int rb  = rem % RB;
    int ch  = rem / RB;

    int ybeg = (int)(((long long)V * ch) / CHUNKS);
    int yend = (int)(((long long)V * (ch + 1)) / CHUNKS);
    int nt = yend - ybeg;                       // <= MAXTILE
    if ((int)threadIdx.x < nt)
        ytile[threadIdx.x] = y_frag(verts, deform, trg, dir, ybeg + threadIdx.x);

    int base = rb * ROWS_PER_BLOCK + (int)threadIdx.x;
    float4 xv[RPT];
    float  best[RPT];
    #pragma unroll
    for (int k = 0; k < RPT; ++k) {
        int idx = base + k * 256;
        xv[k] = x_frag(verts, deform, trg, dir, idx < V ? idx : (V - 1));
        best[k] = INFINITY;
    }
    __syncthreads();
    #pragma unroll 4
    for (int j = 0; j < nt; ++j) {
        float4 yv = ytile[j];                   // broadcast: conflict-free
        #pragma unroll
        for (int k = 0; k < RPT; ++k) {
            float t = fmaf(yv.x, xv[k].x, yv.w);
            t = fmaf(yv.y, xv[k].y, t);
            t = fmaf(yv.z, xv[k].z, t);         // t = yy - 2*x.y (d2 = xx+t)
            best[k] = fminf(best[k], t);
        }
    }
    float* slice = minpart + (size_t)(dir * CHUNKS + ch) * V;
    #pragma unroll
    for (int k = 0; k < RPT; ++k) {
        int idx = base + k * 256;
        if (idx < V) slice[idx] = best[k];      // plain store, written once
    }
}

// ---------------- K2: finalize (vertex gather + edges + quads + reduce) ----
__global__ void fin_kernel(const float* __restrict__ verts,
                           const float* __restrict__ deform,
                           const float* __restrict__ trg,
                           const float* __restrict__ minpart,
                           const int* __restrict__ ev,
                           const int* __restrict__ eo,
                           int V, int E, int F, int Wg,
                           float* __restrict__ out) {
    __shared__ float sbuf[8];
    int t = blockIdx.x * blockDim.x + threadIdx.x;
    float contrib = 0.0f;
    if (t < V) {
        int i = t / Wg, j = t % Wg;
        // 3x3 neighborhoods; newv computed on the fly
        F3 Pn[3][3], Pv[3][3];
        #pragma unroll
        for (int di = -1; di <= 1; ++di) {
            #pragma unroll
            for (int dj = -1; dj <= 1; ++dj) {
                int ii = min(max(i + di, 0), Wg - 1);
                int jj = min(max(j + dj, 0), Wg - 1);
                int idx = ii * Wg + jj;
                F3 v = ld3(verts, idx);
                F3 d = ld3(deform, idx);
                Pv[di+1][dj+1] = v;
                Pn[di+1][dj+1] = add3(v, d);
            }
        }
        F3 vni = {0,0,0}, vnn = {0,0,0}, lv = {0,0,0};
        float rs = 0.0f;
        float c0, c1, c2;
        bool qr = (i <= Wg-2), qd = (j <= Wg-2), qu = (i >= 1), ql = (j >= 1);
        // quad (i,j): v = c00 of t1=(c00,c10,c11), t2=(c00,c11,c01) -> role0 both
        if (qr && qd) {
            F3 n00 = Pn[1][1], n10 = Pn[2][1], n11 = Pn[2][2], n01 = Pn[1][2];
            vnn = add3(vnn, crs3(sub3(n10, n00), sub3(n11, n00)));
            vnn = add3(vnn, crs3(sub3(n11, n00), sub3(n01, n00)));
            F3 m00 = Pv[1][1], m10 = Pv[2][1], m11 = Pv[2][2], m01 = Pv[1][2];
            vni = add3(vni, crs3(sub3(m10, m00), sub3(m11, m00)));
            vni = add3(vni, crs3(sub3(m11, m00), sub3(m01, m00)));
            tri_cots(n00, n10, n11, c0, c1, c2);   // role0: c1*p2 + c2*p1
            lv.x += c1*n11.x + c2*n10.x; lv.y += c1*n11.y + c2*n10.y; lv.z += c1*n11.z + c2*n10.z;
            rs += c1 + c2;
            tri_cots(n00, n11, n01, c0, c1, c2);   // role0
            lv.x += c1*n01.x + c2*n11.x; lv.y += c1*n01.y + c2*n11.y; lv.z += c1*n01.z + c2*n11.z;
            rs += c1 + c2;
        }
        // quad (i,j-1): v = c01 of t2=(c00,c11,c01) -> role2
        if (qr && ql) {
            F3 n00 = Pn[1][0], n11 = Pn[2][1], n01 = Pn[1][1];
            vnn = add3(vnn, crs3(sub3(n11, n00), sub3(n01, n00)));
            F3 m00 = Pv[1][0], m11 = Pv[2][1], m01 = Pv[1][1];
            vni = add3(vni, crs3(sub3(m11, m00), sub3(m01, m00)));
            tri_cots(n00, n11, n01, c0, c1, c2);   // role2: c0*p1 + c1*p0
            lv.x += c0*n11.x + c1*n00.x; lv.y += c0*n11.y + c1*n00.y; lv.z += c0*n11.z + c1*n00.z;
            rs += c0 + c1;
        }
        // quad (i-1,j): v = c10 of t1=(c00,c10,c11) -> role1
        if (qu && qd) {
            F3 n00 = Pn[0][1], n10 = Pn[1][1], n11 = Pn[1][2];
            vnn = add3(vnn, crs3(sub3(n10, n00), sub3(n11, n00)));
            F3 m00 = Pv[0][1], m10 = Pv[1][1], m11 = Pv[1][2];
            vni = add3(vni, crs3(sub3(m10, m00), sub3(m11, m00)));
            tri_cots(n00, n10, n11, c0, c1, c2);   // role1: c0*p2 + c2*p0
            lv.x += c0*n11.x + c2*n00.x; lv.y += c0*n11.y + c2*n00.y; lv.z += c0*n11.z + c2*n00.z;
            rs += c0 + c2;
        }
        // quad (i-1,j-1): v = c11; t1 role2; t2 role1
        if (qu && ql) {
            F3 n00 = Pn[0][0], n10 = Pn[1][0], n11 = Pn[1][1], n01 = Pn[0][1];
            vnn = add3(vnn, crs3(sub3(n10, n00), sub3(n11, n00)));
            vnn = add3(vnn, crs3(sub3(n11, n00), sub3(n01, n00)));
            F3 m00 = Pv[0][0], m10 = Pv[1][0], m11 = Pv[1][1], m01 = Pv[0][1];
            vni = add3(vni, crs3(sub3(m10, m00), sub3(m11, m00)));
            vni = add3(vni, crs3(sub3(m11, m00), sub3(m01, m00)));
            tri_cots(n00, n10, n11, c0, c1, c2);   // role2: c0*p1 + c1*p0
            lv.x += c0*n10.x + c1*n00.x; lv.y += c0*n10.y + c1*n00.y; lv.z += c0*n10.z + c1*n00.z;
            rs += c0 + c1;
            tri_cots(n00, n11, n01, c0, c1, c2);   // role1: c0*p2 + c2*p0
            lv.x += c0*n01.x + c2*n00.x; lv.y += c0*n01.y + c2*n00.y; lv.z += c0*n01.z + c2*n00.z;
            rs += c0 + c2;
        }
        // normal drift + penetration
        float inv_i = 1.0f / fmaxf(len3(vni), EPS_VN);
        F3 ni = {vni.x*inv_i, vni.y*inv_i, vni.z*inv_i};
        float inv_n = 1.0f / fmaxf(len3(vnn), EPS_VN);
        F3 nn = {vnn.x*inv_n, vnn.y*inv_n, vnn.z*inv_n};
        F3 dd = sub3(nn, ni);
        float consist = dd.x*dd.x + dd.y*dd.y + dd.z*dd.z;
        F3 de = ld3(deform, t);
        float pen = fmaxf(-dot3(de, ni), 0.0f);
        // laplacian
        float inv = (rs > 0.0f) ? (1.0f / rs) : 0.0f;
        F3 vc = Pn[1][1];
        F3 dl = {lv.x*inv - vc.x, lv.y*inv - vc.y, lv.z*inv - vc.z};
        float lap = len3(dl);
        // chamfer: reduce partial mins (coalesced slices)
        float mA = INFINITY, mB = INFINITY, mC = INFINITY;
        #pragma unroll 8
        for (int c = 0; c < CHUNKS; ++c) {
            mA = fminf(mA, minpart[(size_t)(0 * CHUNKS + c) * V + t]);
            mB = fminf(mB, minpart[(size_t)(1 * CHUNKS + c) * V + t]);
            mC = fminf(mC, minpart[(size_t)(2 * CHUNKS + c) * V + t]);
        }
        float xxn = dot3(vc, vc);
        F3 tg = ld3(trg, t);
        float xxt = dot3(tg, tg);
        float dA = xxn + mA;
        float dB = xxt + mB;
        float dC = xxn + mC;
        contrib = (dA + dB + 0.2f*dC + 0.1f*lap + (0.1f/3.0f)*consist + 0.1f*pen)
                  / (float)V;
    } else if (t < V + E) {
        int e = t - V;
        int va = ev[2*e], vb = ev[2*e+1];
        int o0 = eo[2*e], o1 = eo[2*e+1];
        F3 pa = add3(ld3(verts, va), ld3(deform, va));
        F3 pb = add3(ld3(verts, vb), ld3(deform, vb));
        F3 p0 = add3(ld3(verts, o0), ld3(deform, o0));
        F3 p1 = add3(ld3(verts, o1), ld3(deform, o1));
        F3 ee = sub3(pb, pa);
        F3 n0 = crs3(ee, sub3(p0, pa));
        F3 n1c = crs3(ee, sub3(p1, pa));
        F3 n1 = {-n1c.x, -n1c.y, -n1c.z};
        float num = dot3(n0, n1);
        float den = fmaxf(len3(n0) * len3(n1), EPS_COS);
        contrib = 0.1f * (1.0f - num / den) / (float)E;
    } else {
        // quad role: edge + smooth terms
        int Q = Wg - 1;
        int q = t - V - E;
        if (q < Q * Q) {
            int qi = q / Q, qj = q % Q;
            int v00 = qi * Wg + qj;
            int v01 = v00 + 1, v10 = v00 + Wg, v11 = v10 + 1;
            F3 d00 = ld3(deform, v00), d01 = ld3(deform, v01),
               d10 = ld3(deform, v10), d11 = ld3(deform, v11);
            F3 b00 = add3(ld3(verts, v00), d00), b01 = add3(ld3(verts, v01), d01),
               b10 = add3(ld3(verts, v10), d10), b11 = add3(ld3(verts, v11), d11);
            // tri1 = (v00, v10, v11); tri2 = (v00, v11, v01)
            float e0 = len3(sub3(b00, b10));
            float e1 = len3(sub3(b10, b11));
            float e2 = len3(sub3(b11, b00));
            float edge = (e0-e1)*(e0-e1) + (e1-e2)*(e1-e2) + (e2-e0)*(e2-e0);
            float f0 = e2;
            float f1 = len3(sub3(b11, b01));
            float f2 = len3(sub3(b01, b00));
            edge += (f0-f1)*(f0-f1) + (f1-f2)*(f1-f2) + (f2-f0)*(f2-f0);
            float sm = l1d(d00, d10) + l1d(d10, d11) + l1d(d11, d00)
                     + l1d(d00, d11) + l1d(d11, d01) + l1d(d01, d00);
            float fF = (float)F;
            contrib = 0.1f * edge / fF + (0.1f/3.0f) * sm / fF;
        }
    }
    float s = blockReduceSum(contrib, sbuf);
    if (threadIdx.x == 0) atomicAdd(out, s);
}

extern "C" void kernel_launch(void* const* d_in, const int* in_sizes, int n_in,
                              void* d_out, int out_size, void* d_ws, size_t ws_size,
                              hipStream_t stream) {
    const float* verts  = (const float*)d_in[0];
    const float* deform = (const float*)d_in[1];
    const float* trg    = (const float*)d_in[2];
    const int*   ev     = (const int*)d_in[4];
    const int*   eo     = (const int*)d_in[5];
    const int V = in_sizes[0] / 3;
    const int F = in_sizes[3] / 3;
    const int E = in_sizes[4] / 2;
    const int Wg = (int)(sqrt((double)V) + 0.5);   // 100 (grid mesh)
    float* out = (float*)d_out;

    float* minpart = (float*)d_ws;                 // [3*CHUNKS][V] = 7.8 MB

    const int B = 256;
    int RB = (V + ROWS_PER_BLOCK - 1) / ROWS_PER_BLOCK;   // 5
    int CB = 3 * RB * CHUNKS;                             // 975 blocks
    mid_kernel<<<dim3(CB), dim3(B), 0, stream>>>(verts, deform, trg, V, minpart, out);

    int NQ = (Wg - 1) * (Wg - 1);                         // 9801 quads
    int finN = V + E + NQ;
    fin_kernel<<<dim3((finN + B - 1) / B), dim3(B), 0, stream>>>(
        verts, deform, trg, minpart, ev, eo, V, E, F, Wg, out);
}

// Round 8
// 96.534 us; speedup vs baseline: 1.0613x; 1.0613x over previous
//
#include <hip/hip_runtime.h>
#include <math.h>

// ---------------------------------------------------------------------------
// Fused mesh-loss -> single f32 scalar. V=10000 (100x100 grid), F=19602, E edges.
// 2 dispatches:
//  mid: pure chamfer. 960 uniform blocks (3 dirs x 10 rowblocks x 32 chunks),
//       x-fragments + LDS y-tiles computed on the fly; per-chunk row-min
//       written by PLAIN STORE into minpart[dir][chunk][row] (written once,
//       no atomics, no init pass). Block 0 zeroes out[0] (fin runs after).
//  fin: vertex gather (normals + cot-laplacian) + edge normal-consistency +
//       quad edge/smooth roles + 96-load min-reduce -> atomicAdd out[0].
// R7 post-mortem: 195-slice reduce + 32-VGPR x-fragment tile suspected for the
// +8us regression. R8: RPT 8->4 (half the x regs), CHUNKS 65->32 (half the
// reduce), same block count. Inner loop still VALU-bound: 16 VALU insts
// (~32cyc) per ds_read_b128 (~12cyc).
// Symmetry chamfer: d2 symmetric under flip -> one direction, weight 0.2.
// Fixed floor in timed window: harness 268MB ws-poison fill (~41us).
// ---------------------------------------------------------------------------

#define EPS_VN 1e-6f
#define EPS_COS 1e-8f
#define CHUNKS 32
#define MAXTILE 316                // ceil(10000/32)=313
#define RPT 4                      // chamfer rows per thread
#define ROWS_PER_BLOCK (256 * RPT) // 1024

struct F3 { float x, y, z; };
__device__ inline F3 ld3(const float* __restrict__ p, int i) {
    return {p[3*i], p[3*i+1], p[3*i+2]};
}
__device__ inline F3 sub3(F3 a, F3 b) { return {a.x-b.x, a.y-b.y, a.z-b.z}; }
__device__ inline F3 add3(F3 a, F3 b) { return {a.x+b.x, a.y+b.y, a.z+b.z}; }
__device__ inline F3 crs3(F3 a, F3 b) {
    return {a.y*b.z - a.z*b.y, a.z*b.x - a.x*b.z, a.x*b.y - a.y*b.x};
}
__device__ inline float dot3(F3 a, F3 b) { return a.x*b.x + a.y*b.y + a.z*b.z; }
__device__ inline float len3(F3 a) { return sqrtf(dot3(a, a)); }
__device__ inline float l1d(F3 a, F3 b) {
    return fabsf(a.x-b.x) + fabsf(a.y-b.y) + fabsf(a.z-b.z);
}

// Valid result in thread 0 only.
__device__ inline float blockReduceSum(float v, float* sbuf) {
    __syncthreads();
    #pragma unroll
    for (int off = 32; off > 0; off >>= 1) v += __shfl_down(v, off, 64);
    int lane = threadIdx.x & 63;
    int wid  = threadIdx.x >> 6;
    if (lane == 0) sbuf[wid] = v;
    __syncthreads();
    float r = 0.0f;
    if (threadIdx.x == 0) {
        int nw = (blockDim.x + 63) >> 6;
        r = sbuf[0];
        for (int w = 1; w < nw; ++w) r += sbuf[w];
    }
    return r;
}

// cots of tri (p0,p1,p2), reference formula (Heron area, clamp 1e-12)
__device__ inline void tri_cots(F3 p0, F3 p1, F3 p2,
                                float& c0, float& c1, float& c2) {
    float a = len3(sub3(p1, p2));
    float b = len3(sub3(p0, p2));
    float c = len3(sub3(p0, p1));
    float s = 0.5f * (a + b + c);
    float area = sqrtf(fmaxf(s*(s-a)*(s-b)*(s-c), 1e-12f));
    float inv4a = 1.0f / (4.0f * area);
    float a2 = a*a, b2 = b*b, c2q = c*c;
    c0 = (b2 + c2q - a2) * inv4a;
    c1 = (a2 + c2q - b2) * inv4a;
    c2 = (a2 + b2 - c2q) * inv4a;
}

// chamfer operand builders (computed on the fly from raw inputs)
__device__ inline float4 x_frag(const float* __restrict__ verts,
                                const float* __restrict__ deform,
                                const float* __restrict__ trg,
                                int dir, int i) {
    if (dir == 1) {
        F3 t = ld3(trg, i);
        return make_float4(t.x, t.y, t.z, dot3(t, t));
    }
    F3 n = add3(ld3(verts, i), ld3(deform, i));
    return make_float4(n.x, n.y, n.z, dot3(n, n));
}
__device__ inline float4 y_frag(const float* __restrict__ verts,
                                const float* __restrict__ deform,
                                const float* __restrict__ trg,
                                int dir, int j) {
    if (dir == 0) {
        F3 t = ld3(trg, j);
        return make_float4(-2.f*t.x, -2.f*t.y, -2.f*t.z, dot3(t, t));
    }
    F3 n = add3(ld3(verts, j), ld3(deform, j));
    float nn = dot3(n, n);
    if (dir == 1) return make_float4(-2.f*n.x, -2.f*n.y, -2.f*n.z, nn);
    return make_float4( 2.f*n.x, -2.f*n.y, -2.f*n.z, nn);  // flip(newv)
}

// ---------------- K1: chamfer partial mins ----------------
__global__ void mid_kernel(const float* __restrict__ verts,
                           const float* __restrict__ deform,
                           const float* __restrict__ trg,
                           int V,
                           float* __restrict__ minpart,   // [3*CHUNKS][V]
                           float* __restrict__ out) {
    __shared__ float4 ytile[MAXTILE];
    int b = blockIdx.x;
    if (b == 0 && threadIdx.x == 0) out[0] = 0.0f;   // mid precedes fin

    int RB  = (V + ROWS_PER_BLOCK - 1) / ROWS_PER_BLOCK;   // 10
    int per = RB * CHUNKS;
    int dir = b / per;
    int rem = b % per;
    int rb  = rem % RB;
    int ch  = rem / RB;

    int ybeg = (int)(((long long)V * ch) / CHUNKS);
    int yend = (int)(((long long)V * (ch + 1)) / CHUNKS);
    int nt = yend - ybeg;                       // <= 313
    for (int jj = (int)threadIdx.x; jj < nt; jj += 256)
        ytile[jj] = y_frag(verts, deform, trg, dir, ybeg + jj);

    int base = rb * ROWS_PER_BLOCK + (int)threadIdx.x;
    float4 xv[RPT];
    float  best[RPT];
    #pragma unroll
    for (int k = 0; k < RPT; ++k) {
        int idx = base + k * 256;
        xv[k] = x_frag(verts, deform, trg, dir, idx < V ? idx : (V - 1));
        best[k] = INFINITY;
    }
    __syncthreads();
    #pragma unroll 4
    for (int j = 0; j < nt; ++j) {
        float4 yv = ytile[j];                   // broadcast: conflict-free
        #pragma unroll
        for (int k = 0; k < RPT; ++k) {
            float t = fmaf(yv.x, xv[k].x, yv.w);
            t = fmaf(yv.y, xv[k].y, t);
            t = fmaf(yv.z, xv[k].z, t);         // t = yy - 2*x.y (d2 = xx+t)
            best[k] = fminf(best[k], t);
        }
    }
    float* slice = minpart + (size_t)(dir * CHUNKS + ch) * V;
    #pragma unroll
    for (int k = 0; k < RPT; ++k) {
        int idx = base + k * 256;
        if (idx < V) slice[idx] = best[k];      // plain store, written once
    }
}

// ---------------- K2: finalize (vertex gather + edges + quads + reduce) ----
__global__ void fin_kernel(const float* __restrict__ verts,
                           const float* __restrict__ deform,
                           const float* __restrict__ trg,
                           const float* __restrict__ minpart,
                           const int* __restrict__ ev,
                           const int* __restrict__ eo,
                           int V, int E, int F, int Wg,
                           float* __restrict__ out) {
    __shared__ float sbuf[8];
    int t = blockIdx.x * blockDim.x + threadIdx.x;
    float contrib = 0.0f;
    if (t < V) {
        int i = t / Wg, j = t % Wg;
        // 3x3 neighborhoods; newv computed on the fly
        F3 Pn[3][3], Pv[3][3];
        #pragma unroll
        for (int di = -1; di <= 1; ++di) {
            #pragma unroll
            for (int dj = -1; dj <= 1; ++dj) {
                int ii = min(max(i + di, 0), Wg - 1);
                int jj = min(max(j + dj, 0), Wg - 1);
                int idx = ii * Wg + jj;
                F3 v = ld3(verts, idx);
                F3 d = ld3(deform, idx);
                Pv[di+1][dj+1] = v;
                Pn[di+1][dj+1] = add3(v, d);
            }
        }
        F3 vni = {0,0,0}, vnn = {0,0,0}, lv = {0,0,0};
        float rs = 0.0f;
        float c0, c1, c2;
        bool qr = (i <= Wg-2), qd = (j <= Wg-2), qu = (i >= 1), ql = (j >= 1);
        // quad (i,j): v = c00 of t1=(c00,c10,c11), t2=(c00,c11,c01) -> role0 both
        if (qr && qd) {
            F3 n00 = Pn[1][1], n10 = Pn[2][1], n11 = Pn[2][2], n01 = Pn[1][2];
            vnn = add3(vnn, crs3(sub3(n10, n00), sub3(n11, n00)));
            vnn = add3(vnn, crs3(sub3(n11, n00), sub3(n01, n00)));
            F3 m00 = Pv[1][1], m10 = Pv[2][1], m11 = Pv[2][2], m01 = Pv[1][2];
            vni = add3(vni, crs3(sub3(m10, m00), sub3(m11, m00)));
            vni = add3(vni, crs3(sub3(m11, m00), sub3(m01, m00)));
            tri_cots(n00, n10, n11, c0, c1, c2);   // role0: c1*p2 + c2*p1
            lv.x += c1*n11.x + c2*n10.x; lv.y += c1*n11.y + c2*n10.y; lv.z += c1*n11.z + c2*n10.z;
            rs += c1 + c2;
            tri_cots(n00, n11, n01, c0, c1, c2);   // role0
            lv.x += c1*n01.x + c2*n11.x; lv.y += c1*n01.y + c2*n11.y; lv.z += c1*n01.z + c2*n11.z;
            rs += c1 + c2;
        }
        // quad (i,j-1): v = c01 of t2=(c00,c11,c01) -> role2
        if (qr && ql) {
            F3 n00 = Pn[1][0], n11 = Pn[2][1], n01 = Pn[1][1];
            vnn = add3(vnn, crs3(sub3(n11, n00), sub3(n01, n00)));
            F3 m00 = Pv[1][0], m11 = Pv[2][1], m01 = Pv[1][1];
            vni = add3(vni, crs3(sub3(m11, m00), sub3(m01, m00)));
            tri_cots(n00, n11, n01, c0, c1, c2);   // role2: c0*p1 + c1*p0
            lv.x += c0*n11.x + c1*n00.x; lv.y += c0*n11.y + c1*n00.y; lv.z += c0*n11.z + c1*n00.z;
            rs += c0 + c1;
        }
        // quad (i-1,j): v = c10 of t1=(c00,c10,c11) -> role1
        if (qu && qd) {
            F3 n00 = Pn[0][1], n10 = Pn[1][1], n11 = Pn[1][2];
            vnn = add3(vnn, crs3(sub3(n10, n00), sub3(n11, n00)));
            F3 m00 = Pv[0][1], m10 = Pv[1][1], m11 = Pv[1][2];
            vni = add3(vni, crs3(sub3(m10, m00), sub3(m11, m00)));
            tri_cots(n00, n10, n11, c0, c1, c2);   // role1: c0*p2 + c2*p0
            lv.x += c0*n11.x + c2*n00.x; lv.y += c0*n11.y + c2*n00.y; lv.z += c0*n11.z + c2*n00.z;
            rs += c0 + c2;
        }
        // quad (i-1,j-1): v = c11; t1 role2; t2 role1
        if (qu && ql) {
            F3 n00 = Pn[0][0], n10 = Pn[1][0], n11 = Pn[1][1], n01 = Pn[0][1];
            vnn = add3(vnn, crs3(sub3(n10, n00), sub3(n11, n00)));
            vnn = add3(vnn, crs3(sub3(n11, n00), sub3(n01, n00)));
            F3 m00 = Pv[0][0], m10 = Pv[1][0], m11 = Pv[1][1], m01 = Pv[0][1];
            vni = add3(vni, crs3(sub3(m10, m00), sub3(m11, m00)));
            vni = add3(vni, crs3(sub3(m11, m00), sub3(m01, m00)));
            tri_cots(n00, n10, n11, c0, c1, c2);   // role2: c0*p1 + c1*p0
            lv.x += c0*n10.x + c1*n00.x; lv.y += c0*n10.y + c1*n00.y; lv.z += c0*n10.z + c1*n00.z;
            rs += c0 + c1;
            tri_cots(n00, n11, n01, c0, c1, c2);   // role1: c0*p2 + c2*p0
            lv.x += c0*n01.x + c2*n00.x; lv.y += c0*n01.y + c2*n00.y; lv.z += c0*n01.z + c2*n00.z;
            rs += c0 + c2;
        }
        // normal drift + penetration
        float inv_i = 1.0f / fmaxf(len3(vni), EPS_VN);
        F3 ni = {vni.x*inv_i, vni.y*inv_i, vni.z*inv_i};
        float inv_n = 1.0f / fmaxf(len3(vnn), EPS_VN);
        F3 nn = {vnn.x*inv_n, vnn.y*inv_n, vnn.z*inv_n};
        F3 dd = sub3(nn, ni);
        float consist = dd.x*dd.x + dd.y*dd.y + dd.z*dd.z;
        F3 de = ld3(deform, t);
        float pen = fmaxf(-dot3(de, ni), 0.0f);
        // laplacian
        float inv = (rs > 0.0f) ? (1.0f / rs) : 0.0f;
        F3 vc = Pn[1][1];
        F3 dl = {lv.x*inv - vc.x, lv.y*inv - vc.y, lv.z*inv - vc.z};
        float lap = len3(dl);
        // chamfer: reduce partial mins (coalesced slices)
        float mA = INFINITY, mB = INFINITY, mC = INFINITY;
        #pragma unroll 8
        for (int c = 0; c < CHUNKS; ++c) {
            mA = fminf(mA, minpart[(size_t)(0 * CHUNKS + c) * V + t]);
            mB = fminf(mB, minpart[(size_t)(1 * CHUNKS + c) * V + t]);
            mC = fminf(mC, minpart[(size_t)(2 * CHUNKS + c) * V + t]);
        }
        float xxn = dot3(vc, vc);
        F3 tg = ld3(trg, t);
        float xxt = dot3(tg, tg);
        float dA = xxn + mA;
        float dB = xxt + mB;
        float dC = xxn + mC;
        contrib = (dA + dB + 0.2f*dC + 0.1f*lap + (0.1f/3.0f)*consist + 0.1f*pen)
                  / (float)V;
    } else if (t < V + E) {
        int e = t - V;
        int va = ev[2*e], vb = ev[2*e+1];
        int o0 = eo[2*e], o1 = eo[2*e+1];
        F3 pa = add3(ld3(verts, va), ld3(deform, va));
        F3 pb = add3(ld3(verts, vb), ld3(deform, vb));
        F3 p0 = add3(ld3(verts, o0), ld3(deform, o0));
        F3 p1 = add3(ld3(verts, o1), ld3(deform, o1));
        F3 ee = sub3(pb, pa);
        F3 n0 = crs3(ee, sub3(p0, pa));
        F3 n1c = crs3(ee, sub3(p1, pa));
        F3 n1 = {-n1c.x, -n1c.y, -n1c.z};
        float num = dot3(n0, n1);
        float den = fmaxf(len3(n0) * len3(n1), EPS_COS);
        contrib = 0.1f * (1.0f - num / den) / (float)E;
    } else {
        // quad role: edge + smooth terms
        int Q = Wg - 1;
        int q = t - V - E;
        if (q < Q * Q) {
            int qi = q / Q, qj = q % Q;
            int v00 = qi * Wg + qj;
            int v01 = v00 + 1, v10 = v00 + Wg, v11 = v10 + 1;
            F3 d00 = ld3(deform, v00), d01 = ld3(deform, v01),
               d10 = ld3(deform, v10), d11 = ld3(deform, v11);
            F3 b00 = add3(ld3(verts, v00), d00), b01 = add3(ld3(verts, v01), d01),
               b10 = add3(ld3(verts, v10), d10), b11 = add3(ld3(verts, v11), d11);
            // tri1 = (v00, v10, v11); tri2 = (v00, v11, v01)
            float e0 = len3(sub3(b00, b10));
            float e1 = len3(sub3(b10, b11));
            float e2 = len3(sub3(b11, b00));
            float edge = (e0-e1)*(e0-e1) + (e1-e2)*(e1-e2) + (e2-e0)*(e2-e0);
            float f0 = e2;
            float f1 = len3(sub3(b11, b01));
            float f2 = len3(sub3(b01, b00));
            edge += (f0-f1)*(f0-f1) + (f1-f2)*(f1-f2) + (f2-f0)*(f2-f0);
            float sm = l1d(d00, d10) + l1d(d10, d11) + l1d(d11, d00)
                     + l1d(d00, d11) + l1d(d11, d01) + l1d(d01, d00);
            float fF = (float)F;
            contrib = 0.1f * edge / fF + (0.1f/3.0f) * sm / fF;
        }
    }
    float s = blockReduceSum(contrib, sbuf);
    if (threadIdx.x == 0) atomicAdd(out, s);
}

extern "C" void kernel_launch(void* const* d_in, const int* in_sizes, int n_in,
                              void* d_out, int out_size, void* d_ws, size_t ws_size,
                              hipStream_t stream) {
    const float* verts  = (const float*)d_in[0];
    const float* deform = (const float*)d_in[1];
    const float* trg    = (const float*)d_in[2];
    const int*   ev     = (const int*)d_in[4];
    const int*   eo     = (const int*)d_in[5];
    const int V = in_sizes[0] / 3;
    const int F = in_sizes[3] / 3;
    const int E = in_sizes[4] / 2;
    const int Wg = (int)(sqrt((double)V) + 0.5);   // 100 (grid mesh)
    float* out = (float*)d_out;

    float* minpart = (float*)d_ws;                 // [3*CHUNKS][V] = 3.84 MB

    const int B = 256;
    int RB = (V + ROWS_PER_BLOCK - 1) / ROWS_PER_BLOCK;   // 10
    int CB = 3 * RB * CHUNKS;                             // 960 blocks
    mid_kernel<<<dim3(CB), dim3(B), 0, stream>>>(verts, deform, trg, V, minpart, out);

    int NQ = (Wg - 1) * (Wg - 1);                         // 9801 quads
    int finN = V + E + NQ;
    fin_kernel<<<dim3((finN + B - 1) / B), dim3(B), 0, stream>>>(
        verts, deform, trg, minpart, ev, eo, V, E, F, Wg, out);
}